// Round 1
// baseline (306.464 us; speedup 1.0000x reference)
//
#include <hip/hip_runtime.h>

// SeesawLoss on MI355X — R4.
// Inputs: d_in[0] = cls_score fp32 (8,16,512,512), d_in[1] = labels i32 (8,512,512),
//         d_in[2] = cum_samples fp32 (16). Output: d_out[0] = scalar loss fp32.
// ws layout (uint32 words):
//   [0 .. 255]     histogram, cacheline-spread: count for class c at word c*16
//   [256 .. 1279]  64 accumulator pairs, pair i at words 256 + i*16 (+0 nll, +1 mask)
//   [1280]         done-counter for fused final reduction
// R1/R2: latency-bound (L3-hit replays equally slow) from low MLP x TLP.
// R3 (209 us): 1px/thread, hoisted scalar loads. Counters show every app kernel
// <77 us (top-5 all harness fills) -> seesaw_k ~40-45 us ~ 3 TB/s, 2x off BW floor.
// R4: 4px/thread float4 loads (16 KB/wave in flight), loads issued BEFORE the
// histp/LDS barrier (one latency instead of two), s_plog in SGPRs via
// readfirstlane (VGPR headroom), final reduction fused via atomic counter.

constexpr int   kC      = 16;
constexpr int   kHW     = 512 * 512;               // 2^18
constexpr float kP      = 0.8f;                    // mitigation exponent
constexpr float kLogEps = -4.605170185988091f;     // ln(0.01)
constexpr int   kNAcc   = 64;                      // spread accumulator pairs
constexpr int   kCtrW   = 256 + kNAcc * 16;        // done-counter word (1280)

__global__ __launch_bounds__(256) void init_ws_k(unsigned int* ws) {
    for (int i = threadIdx.x; i < kCtrW + 1; i += 256) ws[i] = 0u;
}

// 512 blocks (2/CU): block covers 16 KB of labels, 4 int4/thread hoisted.
__global__ __launch_bounds__(256) void hist_k(const int4* __restrict__ lab4,
                                              unsigned int* __restrict__ histp) {
    int base = blockIdx.x * 1024 + threadIdx.x;
    int4 v[4];
    #pragma unroll
    for (int j = 0; j < 4; ++j) v[j] = lab4[base + j * 256];   // contiguous 4 KB per iter
    int cnt[16];
    #pragma unroll
    for (int c = 0; c < 16; ++c) cnt[c] = 0;
    #pragma unroll
    for (int j = 0; j < 4; ++j) {
        #pragma unroll
        for (int c = 0; c < 16; ++c)
            cnt[c] += (v[j].x == c) + (v[j].y == c) + (v[j].z == c) + (v[j].w == c);
    }
    #pragma unroll
    for (int c = 0; c < 16; ++c) {
        int x = cnt[c];
        #pragma unroll
        for (int off = 32; off > 0; off >>= 1) x += __shfl_down(x, off);
        cnt[c] = x;
    }
    __shared__ unsigned int sh[4 * 16];
    int wave = threadIdx.x >> 6, lane = threadIdx.x & 63;
    if (lane == 0) {
        #pragma unroll
        for (int c = 0; c < 16; ++c) sh[wave * 16 + c] = (unsigned)cnt[c];
    }
    __syncthreads();
    int t = threadIdx.x;
    if (t < 16)   // per-class slots 64 B apart
        atomicAdd(&histp[t * 16], sh[t] + sh[16 + t] + sh[32 + t] + sh[48 + t]);
}

__device__ __forceinline__ float comp4(const float4& v, int p) {
    return p == 0 ? v.x : p == 1 ? v.y : p == 2 ? v.z : v.w;   // p compile-time after unroll
}

// 4 pixels/thread: 16 float4 channel loads = 64 data VGPRs, all independent,
// issued before the s_plog barrier so one latency covers both chains.
// 2048 blocks x 256 threads x 4 px = M exactly.
__global__ __launch_bounds__(256, 4) void seesaw_k(const float* __restrict__ cls,
                                                   const int*   __restrict__ labels,
                                                   const float* __restrict__ cum_in,
                                                   const unsigned int* __restrict__ histp,
                                                   float* __restrict__ ws,
                                                   float* __restrict__ out) {
    __shared__ float s_plog[16];
    __shared__ float s_red[8];
    __shared__ int   s_last;
    int t = threadIdx.x;

    int px0 = (blockIdx.x * 256 + t) << 2;         // 4-aligned, never crosses an image
    int b   = px0 >> 18;
    int hw  = px0 & (kHW - 1);
    const float4* pbase = (const float4*)(cls + (long long)b * kC * kHW + hw);
    float4 v[16];
    #pragma unroll
    for (int c = 0; c < 16; ++c) v[c] = pbase[c * (kHW / 4)];   // 16 KB/wave in flight
    int4 lab4 = ((const int4*)labels)[blockIdx.x * 256 + t];

    if (t < 16) {
        float cc = fmaxf((float)histp[t * 16] + cum_in[t], 1.0f);  // clip(cum, 1, inf)
        s_plog[t] = kP * __logf(cc);
    }
    __syncthreads();   // vmcnt(0) drain here also completes the hoisted float4 loads

    float pl[16];      // wave-uniform -> SGPRs via readfirstlane (frees ~15 VGPRs)
    #pragma unroll
    for (int c = 0; c < 16; ++c)
        pl[c] = __int_as_float(__builtin_amdgcn_readfirstlane(__float_as_int(s_plog[c])));

    float lsum = 0.0f, lcnt = 0.0f;
    #pragma unroll
    for (int p = 0; p < 4; ++p) {
        int lab = (p == 0) ? lab4.x : (p == 1) ? lab4.y : (p == 2) ? lab4.z : lab4.w;
        float l[16];
        #pragma unroll
        for (int c = 0; c < 16; ++c) l[c] = comp4(v[c], p);

        float m1 = l[0];
        float llab = l[0];                          // select chain, no dynamic index
        #pragma unroll
        for (int c = 1; c < 16; ++c) {
            m1 = fmaxf(m1, l[c]);
            if (c == lab) llab = l[c];
        }
        float s = 0.0f;
        #pragma unroll
        for (int c = 0; c < 16; ++c) s += __expf(l[c] - m1);
        // log(score_mat[c]) = l[c] - K, K = max(llab, m1 + log s + log EPS)
        float K    = fmaxf(llab, m1 + __logf(s) + kLogEps);
        float plab = s_plog[lab];                   // LDS gather (per-pixel label)

        float m2 = -3.0e38f;
        #pragma unroll
        for (int c = 0; c < 16; ++c) {
            // adj = l + log(mit) + log(comp); both clamp to 0 at c==lab -> adj==llab
            float a = l[c] + fminf(0.0f, pl[c] - plab)
                           + fmaxf(0.0f, 2.0f * (l[c] - K));
            l[c] = a;
            m2 = fmaxf(m2, a);
        }
        float s2 = 0.0f;
        #pragma unroll
        for (int c = 0; c < 16; ++c) s2 += __expf(l[c] - m2);
        float nll = m2 + __logf(s2) - llab;         // -log_softmax(adj)[lab]

        if (lab != 0) { lsum += nll; lcnt += 1.0f; }  // ignore_index = 0
    }

    #pragma unroll
    for (int off = 32; off > 0; off >>= 1) {
        lsum += __shfl_down(lsum, off);
        lcnt += __shfl_down(lcnt, off);
    }
    int wave = t >> 6, lane = t & 63;
    if (lane == 0) { s_red[wave] = lsum; s_red[4 + wave] = lcnt; }
    __syncthreads();
    if (t == 0) {
        float* pair = ws + 256 + (blockIdx.x & (kNAcc - 1)) * 16;   // 64 B-spread pairs
        atomicAdd(&pair[0], s_red[0] + s_red[1] + s_red[2] + s_red[3]);
        atomicAdd(&pair[1], s_red[4] + s_red[5] + s_red[6] + s_red[7]);
        __threadfence();                                            // release pair updates
        unsigned done = atomicAdd((unsigned int*)ws + kCtrW, 1u);
        s_last = (done == gridDim.x - 1) ? 1 : 0;
    }
    __syncthreads();
    if (s_last && t < 64) {                        // fused final reduction (last block)
        __threadfence();                           // acquire side
        float a  = __hip_atomic_load(ws + 256 + t * 16,
                                     __ATOMIC_RELAXED, __HIP_MEMORY_SCOPE_AGENT);
        float bb = __hip_atomic_load(ws + 256 + t * 16 + 1,
                                     __ATOMIC_RELAXED, __HIP_MEMORY_SCOPE_AGENT);
        #pragma unroll
        for (int off = 32; off > 0; off >>= 1) {
            a  += __shfl_down(a, off);
            bb += __shfl_down(bb, off);
        }
        if (t == 0) out[0] = a / bb;
    }
}

extern "C" void kernel_launch(void* const* d_in, const int* in_sizes, int n_in,
                              void* d_out, int out_size, void* d_ws, size_t ws_size,
                              hipStream_t stream) {
    const float* cls    = (const float*)d_in[0];
    const int*   labels = (const int*)d_in[1];
    const float* cum_in = (const float*)d_in[2];
    float* out = (float*)d_out;
    unsigned int* ws = (unsigned int*)d_ws;

    int M  = in_sizes[1];        // 2,097,152 pixels
    int n4 = M / 4;

    init_ws_k<<<1, 256, 0, stream>>>(ws);
    hist_k<<<n4 / 1024, 256, 0, stream>>>((const int4*)labels, ws);
    seesaw_k<<<M / 1024, 256, 0, stream>>>(cls, labels, cum_in, ws, (float*)ws, out);
}